// Round 2
// baseline (95.243 us; speedup 1.0000x reference)
//
#include <hip/hip_runtime.h>
#include <hip/hip_bf16.h>

typedef __attribute__((ext_vector_type(8))) short bf16x8;
typedef __attribute__((ext_vector_type(4))) float f32x4;

#define N_TOT 8192
#define B_IN  4096
#define D_K   256

__device__ __forceinline__ unsigned short f2bf(float x) {
  unsigned u = __float_as_uint(x);
  u = (u + 0x7FFFu + ((u >> 16) & 1u)) >> 16;
  return (unsigned short)u;
}

__global__ void zero_kernel(float* __restrict__ Sp, float* __restrict__ Pp, int* __restrict__ cnt) {
  int i = blockIdx.x * 256 + threadIdx.x;  // 65536 threads
  Sp[i] = 0.f;
  Pp[i] = 0.f;
  if (i < 1024) cnt[i] = 0;
}

// Normalize each (b,v) row, write bf16 X in anchor order (n = v*B + b), fill labN, histogram cnt.
__global__ void norm_kernel(const float* __restrict__ feat,
                            const int* __restrict__ labels,
                            unsigned short* __restrict__ X,
                            int* __restrict__ labN,
                            int* __restrict__ cnt) {
  int n = blockIdx.x * 4 + (threadIdx.x >> 6);
  int l = threadIdx.x & 63;
  int b = n & (B_IN - 1);
  int v = n >> 12;
  const float4 f = *reinterpret_cast<const float4*>(feat + (size_t)(b * 2 + v) * D_K + l * 4);
  float s = f.x * f.x + f.y * f.y + f.z * f.z + f.w * f.w;
#pragma unroll
  for (int m = 1; m < 64; m <<= 1) s += __shfl_xor(s, m);
  float scale = 1.0f / fmaxf(sqrtf(s), 1e-12f);
  ushort4 o;
  o.x = f2bf(f.x * scale);
  o.y = f2bf(f.y * scale);
  o.z = f2bf(f.z * scale);
  o.w = f2bf(f.w * scale);
  *reinterpret_cast<ushort4*>(X + (size_t)n * D_K + l * 4) = o;
  if (l == 0) {
    int lb = labels[b];
    labN[n] = lb;
    if (n < B_IN) atomicAdd(&cnt[lb], 1);  // integer atomic: deterministic
  }
}

// Main: per block, rows [panel*64, +64) x cols [split*2048, +2048), K=256.
// Computes per-row partial S (sum exp(2*dot-2), m!=n) and P (sum 2*dot over same-label m!=n).
__global__ __launch_bounds__(256) void main_kernel(const unsigned short* __restrict__ X,
                                                   const int* __restrict__ labN,
                                                   float* __restrict__ SpA,
                                                   float* __restrict__ PpA) {
  __shared__ __align__(16) char As[32768];
  __shared__ __align__(16) char Bs[32768];
  const int tid = threadIdx.x;
  const int l = tid & 63, w = tid >> 6;
  const int wy = w >> 1, wx = w & 1;
  const int panel = blockIdx.x >> 2;  // 128 panels
  const int split = blockIdx.x & 3;   // 4 splits
  const int rbase = panel * 64;
  const int cbase = split * 2048;
  const int4* Xg = reinterpret_cast<const int4*>(X);  // 32 int4 per row

  // stage A (once) and B(jt=0); swizzle byte ^= (row&7)<<4
#pragma unroll
  for (int i = 0; i < 8; ++i) {
    int c = tid + i * 256;  // 0..2047
    int row = c >> 5, c16 = c & 31;
    int4 vv = Xg[(rbase + row) * 32 + c16];
    *reinterpret_cast<int4*>(As + row * 512 + ((c16 * 16) ^ ((row & 7) << 4))) = vv;
  }
#pragma unroll
  for (int i = 0; i < 8; ++i) {
    int c = tid + i * 256;
    int row = c >> 5, c16 = c & 31;
    int4 vv = Xg[(cbase + row) * 32 + c16];
    *reinterpret_cast<int4*>(Bs + row * 512 + ((c16 * 16) ^ ((row & 7) << 4))) = vv;
  }
  __syncthreads();

  const int lm = l & 15, lh = l >> 4;
  const int s16 = lh * 16;
  const int rowA0 = wy * 32 + lm, rowA1 = rowA0 + 16;
  const int rowB0 = wx * 32 + lm, rowB1 = rowB0 + 16;
  const int baA0 = rowA0 * 512, baA1 = rowA1 * 512;
  const int baB0 = rowB0 * 512, baB1 = rowB1 * 512;
  const int swA = (rowA0 & 7) << 4;  // rowA1 has same low-3 bits
  const int swB = (rowB0 & 7) << 4;

  int labR[2][4];
#pragma unroll
  for (int fi = 0; fi < 2; ++fi)
#pragma unroll
    for (int r = 0; r < 4; ++r) labR[fi][r] = labN[rbase + wy * 32 + fi * 16 + lh * 4 + r];

  float Sl[2][4] = {{0.f, 0.f, 0.f, 0.f}, {0.f, 0.f, 0.f, 0.f}};
  float Pl[2][4] = {{0.f, 0.f, 0.f, 0.f}, {0.f, 0.f, 0.f, 0.f}};
  const int rg0 = rbase + wy * 32 + lh * 4;  // + fi*16 + r

  for (int jt = 0; jt < 32; ++jt) {
    f32x4 acc[2][2];
#pragma unroll
    for (int fi = 0; fi < 2; ++fi)
#pragma unroll
      for (int fj = 0; fj < 2; ++fj) acc[fi][fj] = (f32x4){0.f, 0.f, 0.f, 0.f};

#pragma unroll
    for (int kk = 0; kk < 8; ++kk) {
      int ko = kk * 64 + s16;
      bf16x8 a0 = *reinterpret_cast<const bf16x8*>(As + baA0 + (ko ^ swA));
      bf16x8 a1 = *reinterpret_cast<const bf16x8*>(As + baA1 + (ko ^ swA));
      bf16x8 b0 = *reinterpret_cast<const bf16x8*>(Bs + baB0 + (ko ^ swB));
      bf16x8 b1 = *reinterpret_cast<const bf16x8*>(Bs + baB1 + (ko ^ swB));
      acc[0][0] = __builtin_amdgcn_mfma_f32_16x16x32_bf16(a0, b0, acc[0][0], 0, 0, 0);
      acc[0][1] = __builtin_amdgcn_mfma_f32_16x16x32_bf16(a0, b1, acc[0][1], 0, 0, 0);
      acc[1][0] = __builtin_amdgcn_mfma_f32_16x16x32_bf16(a1, b0, acc[1][0], 0, 0, 0);
      acc[1][1] = __builtin_amdgcn_mfma_f32_16x16x32_bf16(a1, b1, acc[1][1], 0, 0, 0);
    }
    __syncthreads();  // all waves done reading Bs

    const bool more = (jt + 1 < 32);
    int4 stg[8];
    if (more) {
#pragma unroll
      for (int i = 0; i < 8; ++i) {
        int c = tid + i * 256;
        int row = c >> 5, c16 = c & 31;
        stg[i] = Xg[(cbase + (jt + 1) * 64 + row) * 32 + c16];
      }
    }

    // epilogue: exp + masked accumulation (registers only; overlaps staging-load latency)
    const int cgb = cbase + jt * 64 + wx * 32 + lm;
    int cg[2] = {cgb, cgb + 16};
    int labC[2] = {labN[cg[0]], labN[cg[1]]};
#pragma unroll
    for (int fi = 0; fi < 2; ++fi)
#pragma unroll
      for (int fj = 0; fj < 2; ++fj)
#pragma unroll
        for (int r = 0; r < 4; ++r) {
          float vv = acc[fi][fj][r];
          float logit = vv + vv;  // dot / 0.5
          float e = __expf(logit - 2.0f);
          int rg = rg0 + fi * 16 + r;
          bool nd = (rg != cg[fj]);
          Sl[fi][r] += nd ? e : 0.f;
          Pl[fi][r] += (nd && (labR[fi][r] == labC[fj])) ? logit : 0.f;
        }

    if (more) {
#pragma unroll
      for (int i = 0; i < 8; ++i) {
        int c = tid + i * 256;
        int row = c >> 5, c16 = c & 31;
        *reinterpret_cast<int4*>(Bs + row * 512 + ((c16 * 16) ^ ((row & 7) << 4))) = stg[i];
      }
    }
    __syncthreads();
  }

  // cross-lane reduce over the 16 lanes sharing lh, then one writer per (slot,row)
  const int slot = split * 2 + wx;
#pragma unroll
  for (int fi = 0; fi < 2; ++fi)
#pragma unroll
    for (int r = 0; r < 4; ++r) {
      float s = Sl[fi][r], p = Pl[fi][r];
#pragma unroll
      for (int m = 1; m < 16; m <<= 1) {
        s += __shfl_xor(s, m);
        p += __shfl_xor(p, m);
      }
      if (lm == 0) {
        int row = rbase + wy * 32 + fi * 16 + lh * 4 + r;
        SpA[slot * N_TOT + row] = s;
        PpA[slot * N_TOT + row] = p;
      }
    }
}

__global__ void reduce_kernel(const float* __restrict__ Sp, const float* __restrict__ Pp,
                              const int* __restrict__ labN, const int* __restrict__ cnt,
                              float* __restrict__ out) {
  __shared__ float red[4];
  int tid = threadIdx.x;
  float acc = 0.f;
  for (int n = tid; n < N_TOT; n += 256) {
    float S = 0.f, P = 0.f;
#pragma unroll
    for (int s = 0; s < 8; ++s) {
      S += Sp[s * N_TOT + n];
      P += Pp[s * N_TOT + n];
    }
    float np = (float)(2 * cnt[labN[n]] - 1);
    acc += logf(S) + 2.0f - P / np;
  }
#pragma unroll
  for (int m = 1; m < 64; m <<= 1) acc += __shfl_xor(acc, m);
  if ((tid & 63) == 0) red[tid >> 6] = acc;
  __syncthreads();
  if (tid == 0) out[0] = (red[0] + red[1] + red[2] + red[3]) / (float)N_TOT;
}

extern "C" void kernel_launch(void* const* d_in, const int* in_sizes, int n_in,
                              void* d_out, int out_size, void* d_ws, size_t ws_size,
                              hipStream_t stream) {
  const float* feat = (const float*)d_in[0];
  const int* labels = (const int*)d_in[1];
  char* ws = (char*)d_ws;
  unsigned short* X = (unsigned short*)ws;       // 8192*256*2 = 4 MB
  int* labN = (int*)(ws + 4194304);              // 32 KB
  int* cnt = (int*)(ws + 4227072);               // 4 KB
  float* Sp = (float*)(ws + 4231168);            // 8*8192*4 = 256 KB
  float* Pp = (float*)(ws + 4493312);            // 256 KB
  float* out = (float*)d_out;

  zero_kernel<<<256, 256, 0, stream>>>(Sp, Pp, cnt);
  norm_kernel<<<2048, 256, 0, stream>>>(feat, labels, X, labN, cnt);
  main_kernel<<<512, 256, 0, stream>>>(X, labN, Sp, Pp);
  reduce_kernel<<<1, 256, 0, stream>>>(Sp, Pp, labN, cnt, out);
}